// Round 17
// baseline (139.983 us; speedup 1.0000x reference)
//
#include <hip/hip_runtime.h>
#include <hip/hip_bf16.h>
#include <stdint.h>

#define NODES 50000
#define EDGES 800000
#define CAPQ  24        // per-quartile bucket capacity (deg_q ~ Poisson(4), P(>24)~1e-12)
#define NSTR  96        // esrc node stride = 4*CAPQ

typedef __attribute__((ext_vector_type(8))) short bf16x8;
typedef __attribute__((ext_vector_type(8))) unsigned short u16x8;
typedef __attribute__((ext_vector_type(4))) float f32x4;
typedef unsigned short ushort_t;

__device__ __forceinline__ float4 ld4(const float* p) {
    return *reinterpret_cast<const float4*>(p);
}
__device__ __forceinline__ ushort_t f2bf(float f) {   // RNE f32->bf16 bits
    unsigned u = __float_as_uint(f);
    unsigned r = (u + 0x7fff + ((u >> 16) & 1)) >> 16;
    return (ushort_t)r;
}
__device__ __forceinline__ float bf2f(ushort_t h) {
    return __uint_as_float(((unsigned)h) << 16);
}

// ---------------- zero deg4 (plain kernel; rocclr fill path avoided) ----------------
__global__ __launch_bounds__(256) void zerok(unsigned* __restrict__ deg4) {
    int t = blockIdx.x * 256 + threadIdx.x;
    if (t < 25000) reinterpret_cast<uint2*>(deg4)[t] = make_uint2(0u, 0u);
}

// ---------------- monolithic prep (fill ∥ cvt ∥ packs) ----------------
// Fill now quartile-sorts each node's bucket BY SRC RANGE for free:
// deg4[d] holds 4 byte-counters (quartile q = src/12500); one atomicAdd
// of 1<<(8q) yields the slot. esrc[d*96 + q*24 + slot] = src.
__global__ __launch_bounds__(256) void prep(
    const float* __restrict__ x, const int* __restrict__ src,
    const int* __restrict__ dst,
    const float* __restrict__ Wr1, const float* __restrict__ Wl1,
    const float* __restrict__ Wr2, const float* __restrict__ Wl2,
    unsigned* __restrict__ deg4, ushort_t* __restrict__ esrc,
    ushort_t* __restrict__ xbf, ushort_t* __restrict__ w1p,
    ushort_t* __restrict__ w2p) {
    int b = blockIdx.x;
    if (b < 3128) {                       // 391 chunks x 8 XCD groups
        int g = b & 7, chunk = b >> 3;
        int lo = g * 6250;
#pragma unroll
        for (int k = 0; k < 8; ++k) {
            int e = chunk * 2048 + k * 256 + threadIdx.x;
            if (e < EDGES) {
                int d = dst[e];
                if ((unsigned)(d - lo) < 6250u) {
                    unsigned s = (unsigned)src[e];
                    int q = s / 12500u;
                    unsigned old = atomicAdd(&deg4[d], 1u << (8 * q));
                    unsigned sq = (old >> (8 * q)) & 0xffu;
                    if (sq < CAPQ)
                        esrc[(size_t)d * NSTR + q * CAPQ + sq] = (ushort_t)s;
                }
            }
        }
    } else if (b < 9378) {                // 6250*256 == NODES*32 exactly
        int idx = (b - 3128) * 256 + threadIdx.x;
        int i = idx >> 5, c = idx & 31;
        float4 v = ld4(x + (size_t)i * 128 + c * 4);
        ushort4 h;
        h.x = f2bf(v.x); h.y = f2bf(v.y); h.z = f2bf(v.z); h.w = f2bf(v.w);
        *reinterpret_cast<ushort4*>(xbf + (size_t)i * 128 + c * 4) = h;
    } else if (b < 9394) {                // 4096 threads: w1 fragment pack
        int t = (b - 9378) * 256 + threadIdx.x;     // t = (nf*8+kc)*64+lane
        int nf = t >> 9, kc = (t >> 6) & 7, lane = t & 63;
        int r = nf * 16 + (lane & 15);
        int k2 = kc * 32 + ((lane >> 4) << 3);
        u16x8 o;
#pragma unroll
        for (int j = 0; j < 8; ++j) {
            int kk = k2 + j;
            float v = (kk < 128) ? Wr1[r * 128 + kk] : Wl1[r * 128 + (kk - 128)];
            o[j] = f2bf(v);
        }
        *reinterpret_cast<u16x8*>(w1p + (size_t)t * 8) = o;
    } else {                              // 1280 threads: w2 fragment pack
        int t = (b - 9394) * 256 + threadIdx.x;     // t = (nf*4+kc)*64+lane
        if (t >= 1280) return;
        int nf = t >> 8, kc = (t >> 6) & 3, lane = t & 63;
        int r = nf * 16 + (lane & 15);
        int k2 = kc * 32 + ((lane >> 4) << 3);
        u16x8 o;
#pragma unroll
        for (int j = 0; j < 8; ++j) {
            int kk = k2 + j;
            float v = (r < 40) ? Wr2[r * 128 + kk] : Wl2[(r - 40) * 128 + kk];
            o[j] = f2bf(v);
        }
        *reinterpret_cast<u16x8*>(w2p + (size_t)t * 8) = o;
    }
}

// ---------------- layer-1 gather-mean, quartile-sliced, 8-deep MLP ----------------
// 16 lanes/node. Pass q gathers only srcs in [q*12500,(q+1)*12500) — a 3.2 MB
// xbf slice that fits each XCD's 4 MB L2; blocks traverse quartiles in
// near-lockstep so the slice stays resident.
__global__ __launch_bounds__(256) void aggx(
    const ushort_t* __restrict__ xbf, ushort_t* __restrict__ mbf,
    const ushort_t* __restrict__ esrc, const unsigned* __restrict__ deg4) {
    int idx = blockIdx.x * 256 + threadIdx.x;
    int i = idx >> 4, c = idx & 15;
    unsigned d4 = deg4[i];
    int dg = (int)((d4 & 0xffu) + ((d4 >> 8) & 0xffu) +
                   ((d4 >> 16) & 0xffu) + (d4 >> 24));
    float a0[8] = {}, a1[8] = {};
#pragma unroll
    for (int q = 0; q < 4; ++q) {
        int n = (int)((d4 >> (8 * q)) & 0xffu); if (n > CAPQ) n = CAPQ;
        const ushort_t* ep = esrc + (size_t)i * NSTR + q * CAPQ;
        int j = 0;
        for (; j + 8 <= n; j += 8) {
            int s0 = ep[j],     s1 = ep[j + 1], s2 = ep[j + 2], s3 = ep[j + 3];
            int s4 = ep[j + 4], s5 = ep[j + 5], s6 = ep[j + 6], s7 = ep[j + 7];
            u16x8 v0 = *reinterpret_cast<const u16x8*>(xbf + (size_t)s0 * 128 + c * 8);
            u16x8 v1 = *reinterpret_cast<const u16x8*>(xbf + (size_t)s1 * 128 + c * 8);
            u16x8 v2 = *reinterpret_cast<const u16x8*>(xbf + (size_t)s2 * 128 + c * 8);
            u16x8 v3 = *reinterpret_cast<const u16x8*>(xbf + (size_t)s3 * 128 + c * 8);
            u16x8 v4 = *reinterpret_cast<const u16x8*>(xbf + (size_t)s4 * 128 + c * 8);
            u16x8 v5 = *reinterpret_cast<const u16x8*>(xbf + (size_t)s5 * 128 + c * 8);
            u16x8 v6 = *reinterpret_cast<const u16x8*>(xbf + (size_t)s6 * 128 + c * 8);
            u16x8 v7 = *reinterpret_cast<const u16x8*>(xbf + (size_t)s7 * 128 + c * 8);
#pragma unroll
            for (int k = 0; k < 8; ++k) {
                a0[k] += (bf2f(v0[k]) + bf2f(v2[k])) + (bf2f(v4[k]) + bf2f(v6[k]));
                a1[k] += (bf2f(v1[k]) + bf2f(v3[k])) + (bf2f(v5[k]) + bf2f(v7[k]));
            }
        }
        for (; j + 4 <= n; j += 4) {
            int s0 = ep[j], s1 = ep[j + 1], s2 = ep[j + 2], s3 = ep[j + 3];
            u16x8 v0 = *reinterpret_cast<const u16x8*>(xbf + (size_t)s0 * 128 + c * 8);
            u16x8 v1 = *reinterpret_cast<const u16x8*>(xbf + (size_t)s1 * 128 + c * 8);
            u16x8 v2 = *reinterpret_cast<const u16x8*>(xbf + (size_t)s2 * 128 + c * 8);
            u16x8 v3 = *reinterpret_cast<const u16x8*>(xbf + (size_t)s3 * 128 + c * 8);
#pragma unroll
            for (int k = 0; k < 8; ++k) {
                a0[k] += bf2f(v0[k]) + bf2f(v2[k]);
                a1[k] += bf2f(v1[k]) + bf2f(v3[k]);
            }
        }
        for (; j < n; ++j) {
            int s = ep[j];
            u16x8 v = *reinterpret_cast<const u16x8*>(xbf + (size_t)s * 128 + c * 8);
#pragma unroll
            for (int k = 0; k < 8; ++k) a0[k] += bf2f(v[k]);
        }
    }
    float ci = 1.0f / fmaxf((float)dg, 1.0f);
    u16x8 m;
#pragma unroll
    for (int k = 0; k < 8; ++k) m[k] = f2bf((a0[k] + a1[k]) * ci);
    *reinterpret_cast<u16x8*>(mbf + (size_t)i * 128 + c * 8) = m;
}

// ---------------- fused GEMM1 + GEMM2 (packed weights, split A, split V) ----------------
// Phase 1: emb = [xbf | mbf] @ W1^T + b1; emb NT-stored; relu->bf16 LDS hs
// Phase 2: cols 0..39 -> Vself[row*48+col], cols 40..79 -> Vn[row*48+col-40]
//          (stride 48 ushorts = 96B keeps 16B alignment; Vn dense ~L2-fits)
__global__ __launch_bounds__(256) void gemm12(
    const ushort_t* __restrict__ xbf, const ushort_t* __restrict__ mbf,
    const ushort_t* __restrict__ w1p, const ushort_t* __restrict__ w2p,
    const float* __restrict__ b1, float* __restrict__ emb,
    ushort_t* __restrict__ Vself, ushort_t* __restrict__ Vn, int M) {
    __shared__ ushort_t hs[64][136];      // stride 136: 16B-aligned rows
    const int wave = threadIdx.x >> 6, lane = threadIdx.x & 63;
    const int r0 = blockIdx.x * 64 + wave * 16;
    int arow = r0 + (lane & 15); if (arow >= M) arow = M - 1;
    const int klane = (lane >> 4) * 8;

    f32x4 acc[8] = {};
#pragma unroll
    for (int kc = 0; kc < 8; ++kc) {
        bf16x8 a = (kc < 4)
            ? *reinterpret_cast<const bf16x8*>(xbf + (size_t)arow * 128 + kc * 32 + klane)
            : *reinterpret_cast<const bf16x8*>(mbf + (size_t)arow * 128 + (kc - 4) * 32 + klane);
        bf16x8 wv[8];
#pragma unroll
        for (int nf = 0; nf < 8; ++nf)
            wv[nf] = *reinterpret_cast<const bf16x8*>(
                w1p + (size_t)((nf * 8 + kc) * 64 + lane) * 8);
#pragma unroll
        for (int nf = 0; nf < 8; ++nf)
            acc[nf] = __builtin_amdgcn_mfma_f32_16x16x32_bf16(a, wv[nf], acc[nf], 0, 0, 0);
    }

    const int crow0r = wave * 16 + (lane >> 4) * 4;     // row within tile
    const int crow0  = blockIdx.x * 64 + crow0r;
    const int ccol   = lane & 15;
#pragma unroll
    for (int nf = 0; nf < 8; ++nf) {
        int col = nf * 16 + ccol;
        float bv = b1[col];
#pragma unroll
        for (int r = 0; r < 4; ++r) {
            int row = crow0 + r;
            float val = acc[nf][r] + bv;
            if (row < M)
                __builtin_nontemporal_store(val, emb + (size_t)row * 128 + col);
            hs[crow0r + r][col] = f2bf(fmaxf(val, 0.f));
        }
    }
    __syncthreads();

    f32x4 acc2[5] = {};
#pragma unroll
    for (int kc = 0; kc < 4; ++kc) {
        bf16x8 a = *reinterpret_cast<const bf16x8*>(
            &hs[wave * 16 + (lane & 15)][kc * 32 + klane]);
        bf16x8 wv[5];
#pragma unroll
        for (int nf = 0; nf < 5; ++nf)
            wv[nf] = *reinterpret_cast<const bf16x8*>(
                w2p + (size_t)((nf * 4 + kc) * 64 + lane) * 8);
#pragma unroll
        for (int nf = 0; nf < 5; ++nf)
            acc2[nf] = __builtin_amdgcn_mfma_f32_16x16x32_bf16(a, wv[nf], acc2[nf], 0, 0, 0);
    }
#pragma unroll
    for (int nf = 0; nf < 5; ++nf) {
        int col = nf * 16 + ccol;
#pragma unroll
        for (int r = 0; r < 4; ++r) {
            int row = crow0 + r;
            if (row < M) {
                ushort_t hv = f2bf(acc2[nf][r]);
                if (col < 40) Vself[(size_t)row * 48 + col] = hv;
                else          Vn[(size_t)row * 48 + (col - 40)] = hv;
            }
        }
    }
}

// ---------------- layer-2 gather-mean + epilogue, quartile buckets ----------------
// 8 lanes/node, lanes 0..4 carry ushort8 (40 cols); logits = self + mean + b2.
__global__ __launch_bounds__(256) void agg2(
    const ushort_t* __restrict__ Vself, const ushort_t* __restrict__ Vn,
    const ushort_t* __restrict__ esrc, const unsigned* __restrict__ deg4,
    const float* __restrict__ b2, float* __restrict__ logits) {
    int idx = blockIdx.x * 256 + threadIdx.x;
    int i = idx >> 3, c = idx & 7;
    if (i >= NODES || c >= 5) return;
    unsigned d4 = deg4[i];
    int dg = (int)((d4 & 0xffu) + ((d4 >> 8) & 0xffu) +
                   ((d4 >> 16) & 0xffu) + (d4 >> 24));
    float a0[8] = {}, a1[8] = {};
#pragma unroll
    for (int q = 0; q < 4; ++q) {
        int n = (int)((d4 >> (8 * q)) & 0xffu); if (n > CAPQ) n = CAPQ;
        const ushort_t* ep = esrc + (size_t)i * NSTR + q * CAPQ;
        int j = 0;
        for (; j + 8 <= n; j += 8) {
            int s0 = ep[j],     s1 = ep[j + 1], s2 = ep[j + 2], s3 = ep[j + 3];
            int s4 = ep[j + 4], s5 = ep[j + 5], s6 = ep[j + 6], s7 = ep[j + 7];
            u16x8 v0 = *reinterpret_cast<const u16x8*>(Vn + (size_t)s0 * 48 + c * 8);
            u16x8 v1 = *reinterpret_cast<const u16x8*>(Vn + (size_t)s1 * 48 + c * 8);
            u16x8 v2 = *reinterpret_cast<const u16x8*>(Vn + (size_t)s2 * 48 + c * 8);
            u16x8 v3 = *reinterpret_cast<const u16x8*>(Vn + (size_t)s3 * 48 + c * 8);
            u16x8 v4 = *reinterpret_cast<const u16x8*>(Vn + (size_t)s4 * 48 + c * 8);
            u16x8 v5 = *reinterpret_cast<const u16x8*>(Vn + (size_t)s5 * 48 + c * 8);
            u16x8 v6 = *reinterpret_cast<const u16x8*>(Vn + (size_t)s6 * 48 + c * 8);
            u16x8 v7 = *reinterpret_cast<const u16x8*>(Vn + (size_t)s7 * 48 + c * 8);
#pragma unroll
            for (int k = 0; k < 8; ++k) {
                a0[k] += (bf2f(v0[k]) + bf2f(v2[k])) + (bf2f(v4[k]) + bf2f(v6[k]));
                a1[k] += (bf2f(v1[k]) + bf2f(v3[k])) + (bf2f(v5[k]) + bf2f(v7[k]));
            }
        }
        for (; j + 4 <= n; j += 4) {
            int s0 = ep[j], s1 = ep[j + 1], s2 = ep[j + 2], s3 = ep[j + 3];
            u16x8 v0 = *reinterpret_cast<const u16x8*>(Vn + (size_t)s0 * 48 + c * 8);
            u16x8 v1 = *reinterpret_cast<const u16x8*>(Vn + (size_t)s1 * 48 + c * 8);
            u16x8 v2 = *reinterpret_cast<const u16x8*>(Vn + (size_t)s2 * 48 + c * 8);
            u16x8 v3 = *reinterpret_cast<const u16x8*>(Vn + (size_t)s3 * 48 + c * 8);
#pragma unroll
            for (int k = 0; k < 8; ++k) {
                a0[k] += bf2f(v0[k]) + bf2f(v2[k]);
                a1[k] += bf2f(v1[k]) + bf2f(v3[k]);
            }
        }
        for (; j < n; ++j) {
            int s = ep[j];
            u16x8 v = *reinterpret_cast<const u16x8*>(Vn + (size_t)s * 48 + c * 8);
#pragma unroll
            for (int k = 0; k < 8; ++k) a0[k] += bf2f(v[k]);
        }
    }
    float ci = 1.0f / fmaxf((float)dg, 1.0f);
    u16x8 sv = *reinterpret_cast<const u16x8*>(Vself + (size_t)i * 48 + c * 8);
    float o[8];
#pragma unroll
    for (int k = 0; k < 8; ++k)
        o[k] = bf2f(sv[k]) + (a0[k] + a1[k]) * ci + b2[c * 8 + k];
    float4* dst4 = reinterpret_cast<float4*>(logits + (size_t)i * 40 + c * 8);
    dst4[0] = make_float4(o[0], o[1], o[2], o[3]);
    dst4[1] = make_float4(o[4], o[5], o[6], o[7]);
}

extern "C" void kernel_launch(void* const* d_in, const int* in_sizes, int n_in,
                              void* d_out, int out_size, void* d_ws, size_t ws_size,
                              hipStream_t stream) {
    const float* x   = (const float*)d_in[0];
    const int*   ei  = (const int*)d_in[1];
    const float* Wl1 = (const float*)d_in[2];
    const float* Wr1 = (const float*)d_in[3];
    const float* b1  = (const float*)d_in[4];
    const float* Wl2 = (const float*)d_in[5];
    const float* Wr2 = (const float*)d_in[6];
    const float* b2  = (const float*)d_in[7];
    const int* src = ei;              // edge_index[0]
    const int* dst = ei + EDGES;      // edge_index[1]

    // Workspace (~45.2 MB):
    //   [0, 12.8M)       xbf [50000x128 bf16]
    //   [12.8M, 25.6M)   mbf [50000x128 bf16]
    //   [25.6M, 30.4M)   Vself [50000x48 bf16] (cols 0..39 used)
    //   [30.4M, 35.2M)   Vn    [50000x48 bf16] (cols 0..39 used)
    //   [35.2M, 44.8M)   esrc [50000*96 ushort] (4 quartile sub-buckets x 24)
    //   [44.8M, 45.0M)   deg4 [50000 u32]
    //   [45.0M, ...)     w1p, w2p packed bf16
    char* ws = (char*)d_ws;
    ushort_t* xbf   = (ushort_t*)ws;
    ushort_t* mbf   = (ushort_t*)(ws + 12800000);
    ushort_t* Vself = (ushort_t*)(ws + 25600000);
    ushort_t* Vn    = (ushort_t*)(ws + 30400000);
    ushort_t* esrc  = (ushort_t*)(ws + 35200000);
    unsigned* deg4  = (unsigned*)(ws + 44800000);
    ushort_t* w1p   = (ushort_t*)(ws + 45000000);
    ushort_t* w2p   = (ushort_t*)(ws + 45065536);

    float* logits_out = (float*)d_out;                   // 50000*40 f32
    float* emb_out    = logits_out + (size_t)NODES * 40; // 50000*128 f32

    zerok<<<98, 256, 0, stream>>>(deg4);

    prep<<<9399, 256, 0, stream>>>(x, src, dst, Wr1, Wl1, Wr2, Wl2,
                                   deg4, esrc, xbf, w1p, w2p);

    aggx<<<3125, 256, 0, stream>>>(xbf, mbf, esrc, deg4);

    gemm12<<<(NODES + 63) / 64, 256, 0, stream>>>(xbf, mbf, w1p, w2p, b1,
                                                  emb_out, Vself, Vn, NODES);

    agg2<<<(NODES * 8 + 255) / 256, 256, 0, stream>>>(Vself, Vn, esrc, deg4,
                                                      b2, logits_out);
}

// Round 18
// 119.563 us; speedup vs baseline: 1.1708x; 1.1708x over previous
//
#include <hip/hip_runtime.h>
#include <hip/hip_bf16.h>
#include <stdint.h>

#define NODES 50000
#define EDGES 800000
#define CAP   64        // per-node bucket capacity (deg ~ Poisson(16))

typedef __attribute__((ext_vector_type(8))) short bf16x8;
typedef __attribute__((ext_vector_type(8))) unsigned short u16x8;
typedef __attribute__((ext_vector_type(4))) float f32x4;
typedef unsigned short ushort_t;

__device__ __forceinline__ float4 ld4(const float* p) {
    return *reinterpret_cast<const float4*>(p);
}
__device__ __forceinline__ ushort_t f2bf(float f) {   // RNE f32->bf16 bits
    unsigned u = __float_as_uint(f);
    unsigned r = (u + 0x7fff + ((u >> 16) & 1)) >> 16;
    return (ushort_t)r;
}
__device__ __forceinline__ float bf2f(ushort_t h) {
    return __uint_as_float(((unsigned)h) << 16);
}

// ---------------- zero deg (plain kernel; rocclr fill path avoided) ----------------
__global__ __launch_bounds__(256) void zerok(int* __restrict__ deg) {
    int t = blockIdx.x * 256 + threadIdx.x;
    if (t < 25000) reinterpret_cast<int2*>(deg)[t] = make_int2(0, 0);
}

// ---------------- monolithic prep (measured-best R14 structure) ----------------
// blocks [0,3128):      XCD-partitioned bucket fill (group g = b&7 owns nodes
//                       [g*6250,(g+1)*6250); round-robin block->XCD keeps each
//                       group's esrc/deg slice in one L2)
// blocks [3128,9378):   x -> bf16 into A1 cols 0..127 (overlaps with fill)
// blocks [9378,9394):   pack w1 into MFMA fragment order
// blocks [9394,9399):   pack w2 likewise
__global__ __launch_bounds__(256) void prep(
    const float* __restrict__ x, const int* __restrict__ src,
    const int* __restrict__ dst,
    const float* __restrict__ Wr1, const float* __restrict__ Wl1,
    const float* __restrict__ Wr2, const float* __restrict__ Wl2,
    int* __restrict__ deg, ushort_t* __restrict__ esrc,
    ushort_t* __restrict__ A1, ushort_t* __restrict__ w1p,
    ushort_t* __restrict__ w2p) {
    int b = blockIdx.x;
    if (b < 3128) {                       // 391 chunks x 8 groups
        int g = b & 7, chunk = b >> 3;
        int lo = g * 6250;
#pragma unroll
        for (int k = 0; k < 8; ++k) {
            int e = chunk * 2048 + k * 256 + threadIdx.x;
            if (e < EDGES) {
                int d = dst[e];
                if ((unsigned)(d - lo) < 6250u) {
                    int s = src[e];
                    int p = atomicAdd(&deg[d], 1);
                    if (p < CAP) esrc[(size_t)d * CAP + p] = (ushort_t)s;
                }
            }
        }
    } else if (b < 9378) {                // 6250*256 == NODES*32 exactly
        int idx = (b - 3128) * 256 + threadIdx.x;
        int i = idx >> 5, c = idx & 31;
        float4 v = ld4(x + (size_t)i * 128 + c * 4);
        ushort4 h;
        h.x = f2bf(v.x); h.y = f2bf(v.y); h.z = f2bf(v.z); h.w = f2bf(v.w);
        *reinterpret_cast<ushort4*>(A1 + (size_t)i * 256 + c * 4) = h;
    } else if (b < 9394) {                // 4096 threads: w1 fragment pack
        int t = (b - 9378) * 256 + threadIdx.x;     // t = (nf*8+kc)*64+lane
        int nf = t >> 9, kc = (t >> 6) & 7, lane = t & 63;
        int r = nf * 16 + (lane & 15);
        int k2 = kc * 32 + ((lane >> 4) << 3);
        u16x8 o;
#pragma unroll
        for (int j = 0; j < 8; ++j) {
            int kk = k2 + j;
            float v = (kk < 128) ? Wr1[r * 128 + kk] : Wl1[r * 128 + (kk - 128)];
            o[j] = f2bf(v);
        }
        *reinterpret_cast<u16x8*>(w1p + (size_t)t * 8) = o;
    } else {                              // 1280 threads: w2 fragment pack
        int t = (b - 9394) * 256 + threadIdx.x;     // t = (nf*4+kc)*64+lane
        if (t >= 1280) return;
        int nf = t >> 8, kc = (t >> 6) & 3, lane = t & 63;
        int r = nf * 16 + (lane & 15);
        int k2 = kc * 32 + ((lane >> 4) << 3);
        u16x8 o;
#pragma unroll
        for (int j = 0; j < 8; ++j) {
            int kk = k2 + j;
            float v = (r < 40) ? Wr2[r * 128 + kk] : Wl2[(r - 40) * 128 + kk];
            o[j] = f2bf(v);
        }
        *reinterpret_cast<u16x8*>(w2p + (size_t)t * 8) = o;
    }
}

// ---------------- layer-1 gather-mean (bf16), 8-deep MLP ----------------
// 16 lanes/node, ushort8 (16B) per lane; 8 neighbors in flight, 2 acc chains.
__global__ __launch_bounds__(256) void aggx(
    ushort_t* __restrict__ A1, const ushort_t* __restrict__ esrc,
    const int* __restrict__ deg) {
    int idx = blockIdx.x * 256 + threadIdx.x;
    int i = idx >> 4, c = idx & 15;
    int dg = deg[i];
    int n = dg < CAP ? dg : CAP;
    const ushort_t* ep = esrc + (size_t)i * CAP;
    float a0[8] = {}, a1[8] = {};
    int j = 0;
    for (; j + 8 <= n; j += 8) {
        int s0 = ep[j],     s1 = ep[j + 1], s2 = ep[j + 2], s3 = ep[j + 3];
        int s4 = ep[j + 4], s5 = ep[j + 5], s6 = ep[j + 6], s7 = ep[j + 7];
        u16x8 v0 = *reinterpret_cast<const u16x8*>(A1 + (size_t)s0 * 256 + c * 8);
        u16x8 v1 = *reinterpret_cast<const u16x8*>(A1 + (size_t)s1 * 256 + c * 8);
        u16x8 v2 = *reinterpret_cast<const u16x8*>(A1 + (size_t)s2 * 256 + c * 8);
        u16x8 v3 = *reinterpret_cast<const u16x8*>(A1 + (size_t)s3 * 256 + c * 8);
        u16x8 v4 = *reinterpret_cast<const u16x8*>(A1 + (size_t)s4 * 256 + c * 8);
        u16x8 v5 = *reinterpret_cast<const u16x8*>(A1 + (size_t)s5 * 256 + c * 8);
        u16x8 v6 = *reinterpret_cast<const u16x8*>(A1 + (size_t)s6 * 256 + c * 8);
        u16x8 v7 = *reinterpret_cast<const u16x8*>(A1 + (size_t)s7 * 256 + c * 8);
#pragma unroll
        for (int k = 0; k < 8; ++k) {
            a0[k] += (bf2f(v0[k]) + bf2f(v2[k])) + (bf2f(v4[k]) + bf2f(v6[k]));
            a1[k] += (bf2f(v1[k]) + bf2f(v3[k])) + (bf2f(v5[k]) + bf2f(v7[k]));
        }
    }
    for (; j + 4 <= n; j += 4) {
        int s0 = ep[j], s1 = ep[j + 1], s2 = ep[j + 2], s3 = ep[j + 3];
        u16x8 v0 = *reinterpret_cast<const u16x8*>(A1 + (size_t)s0 * 256 + c * 8);
        u16x8 v1 = *reinterpret_cast<const u16x8*>(A1 + (size_t)s1 * 256 + c * 8);
        u16x8 v2 = *reinterpret_cast<const u16x8*>(A1 + (size_t)s2 * 256 + c * 8);
        u16x8 v3 = *reinterpret_cast<const u16x8*>(A1 + (size_t)s3 * 256 + c * 8);
#pragma unroll
        for (int k = 0; k < 8; ++k) {
            a0[k] += bf2f(v0[k]) + bf2f(v2[k]);
            a1[k] += bf2f(v1[k]) + bf2f(v3[k]);
        }
    }
    for (; j < n; ++j) {
        int s = ep[j];
        u16x8 v = *reinterpret_cast<const u16x8*>(A1 + (size_t)s * 256 + c * 8);
#pragma unroll
        for (int k = 0; k < 8; ++k) a0[k] += bf2f(v[k]);
    }
    float ci = 1.0f / fmaxf((float)dg, 1.0f);
    u16x8 m;
#pragma unroll
    for (int k = 0; k < 8; ++k) m[k] = f2bf((a0[k] + a1[k]) * ci);
    *reinterpret_cast<u16x8*>(A1 + (size_t)i * 256 + 128 + c * 8) = m;
}

// ---------------- fused GEMM1 + GEMM2 (packed weights) ----------------
// Phase 1: emb[64 rows x 128] = A1[rows,256] @ W1^T + b1; relu->bf16 LDS tile
//          emb stored NT (never re-read on device -> keep V/esrc in L2)
// Phase 2: V[rows x 80] = h_lds[rows,128] @ W2^T -> bf16
__global__ __launch_bounds__(256) void gemm12(
    const ushort_t* __restrict__ A1, const ushort_t* __restrict__ w1p,
    const ushort_t* __restrict__ w2p, const float* __restrict__ b1,
    float* __restrict__ emb, ushort_t* __restrict__ V, int M) {
    __shared__ ushort_t hs[64][136];      // stride 136: 16B-aligned rows
    const int wave = threadIdx.x >> 6, lane = threadIdx.x & 63;
    const int r0 = blockIdx.x * 64 + wave * 16;
    int arow = r0 + (lane & 15); if (arow >= M) arow = M - 1;
    const int klane = (lane >> 4) * 8;

    f32x4 acc[8] = {};
#pragma unroll
    for (int kc = 0; kc < 8; ++kc) {
        bf16x8 a = *reinterpret_cast<const bf16x8*>(A1 + (size_t)arow * 256 + kc * 32 + klane);
        bf16x8 wv[8];
#pragma unroll
        for (int nf = 0; nf < 8; ++nf)
            wv[nf] = *reinterpret_cast<const bf16x8*>(
                w1p + (size_t)((nf * 8 + kc) * 64 + lane) * 8);
#pragma unroll
        for (int nf = 0; nf < 8; ++nf)
            acc[nf] = __builtin_amdgcn_mfma_f32_16x16x32_bf16(a, wv[nf], acc[nf], 0, 0, 0);
    }

    const int crow0r = wave * 16 + (lane >> 4) * 4;     // row within tile
    const int crow0  = blockIdx.x * 64 + crow0r;
    const int ccol   = lane & 15;
#pragma unroll
    for (int nf = 0; nf < 8; ++nf) {
        int col = nf * 16 + ccol;
        float bv = b1[col];
#pragma unroll
        for (int r = 0; r < 4; ++r) {
            int row = crow0 + r;
            float val = acc[nf][r] + bv;
            if (row < M)
                __builtin_nontemporal_store(val, emb + (size_t)row * 128 + col);
            hs[crow0r + r][col] = f2bf(fmaxf(val, 0.f));
        }
    }
    __syncthreads();

    f32x4 acc2[5] = {};
#pragma unroll
    for (int kc = 0; kc < 4; ++kc) {
        bf16x8 a = *reinterpret_cast<const bf16x8*>(
            &hs[wave * 16 + (lane & 15)][kc * 32 + klane]);
        bf16x8 wv[5];
#pragma unroll
        for (int nf = 0; nf < 5; ++nf)
            wv[nf] = *reinterpret_cast<const bf16x8*>(
                w2p + (size_t)((nf * 4 + kc) * 64 + lane) * 8);
#pragma unroll
        for (int nf = 0; nf < 5; ++nf)
            acc2[nf] = __builtin_amdgcn_mfma_f32_16x16x32_bf16(a, wv[nf], acc2[nf], 0, 0, 0);
    }
#pragma unroll
    for (int nf = 0; nf < 5; ++nf) {
        int col = nf * 16 + ccol;
#pragma unroll
        for (int r = 0; r < 4; ++r) {
            int row = crow0 + r;
            if (row < M) V[(size_t)row * 80 + col] = f2bf(acc2[nf][r]);
        }
    }
}

// ---------------- layer-2 gather-mean + epilogue (bf16 V), 8-deep MLP ----------------
// 8 lanes/node, lanes 0..4 carry ushort8 (40 cols); logits = self + mean + b2.
__global__ __launch_bounds__(256) void agg2(
    const ushort_t* __restrict__ V, const ushort_t* __restrict__ esrc,
    const int* __restrict__ deg, const float* __restrict__ b2,
    float* __restrict__ logits) {
    int idx = blockIdx.x * 256 + threadIdx.x;
    int i = idx >> 3, c = idx & 7;
    if (i >= NODES || c >= 5) return;
    int dg = deg[i];
    int n = dg < CAP ? dg : CAP;
    const ushort_t* ep = esrc + (size_t)i * CAP;
    float a0[8] = {}, a1[8] = {};
    int j = 0;
    for (; j + 8 <= n; j += 8) {
        int s0 = ep[j],     s1 = ep[j + 1], s2 = ep[j + 2], s3 = ep[j + 3];
        int s4 = ep[j + 4], s5 = ep[j + 5], s6 = ep[j + 6], s7 = ep[j + 7];
        u16x8 v0 = *reinterpret_cast<const u16x8*>(V + (size_t)s0 * 80 + 40 + c * 8);
        u16x8 v1 = *reinterpret_cast<const u16x8*>(V + (size_t)s1 * 80 + 40 + c * 8);
        u16x8 v2 = *reinterpret_cast<const u16x8*>(V + (size_t)s2 * 80 + 40 + c * 8);
        u16x8 v3 = *reinterpret_cast<const u16x8*>(V + (size_t)s3 * 80 + 40 + c * 8);
        u16x8 v4 = *reinterpret_cast<const u16x8*>(V + (size_t)s4 * 80 + 40 + c * 8);
        u16x8 v5 = *reinterpret_cast<const u16x8*>(V + (size_t)s5 * 80 + 40 + c * 8);
        u16x8 v6 = *reinterpret_cast<const u16x8*>(V + (size_t)s6 * 80 + 40 + c * 8);
        u16x8 v7 = *reinterpret_cast<const u16x8*>(V + (size_t)s7 * 80 + 40 + c * 8);
#pragma unroll
        for (int k = 0; k < 8; ++k) {
            a0[k] += (bf2f(v0[k]) + bf2f(v2[k])) + (bf2f(v4[k]) + bf2f(v6[k]));
            a1[k] += (bf2f(v1[k]) + bf2f(v3[k])) + (bf2f(v5[k]) + bf2f(v7[k]));
        }
    }
    for (; j + 4 <= n; j += 4) {
        int s0 = ep[j], s1 = ep[j + 1], s2 = ep[j + 2], s3 = ep[j + 3];
        u16x8 v0 = *reinterpret_cast<const u16x8*>(V + (size_t)s0 * 80 + 40 + c * 8);
        u16x8 v1 = *reinterpret_cast<const u16x8*>(V + (size_t)s1 * 80 + 40 + c * 8);
        u16x8 v2 = *reinterpret_cast<const u16x8*>(V + (size_t)s2 * 80 + 40 + c * 8);
        u16x8 v3 = *reinterpret_cast<const u16x8*>(V + (size_t)s3 * 80 + 40 + c * 8);
#pragma unroll
        for (int k = 0; k < 8; ++k) {
            a0[k] += bf2f(v0[k]) + bf2f(v2[k]);
            a1[k] += bf2f(v1[k]) + bf2f(v3[k]);
        }
    }
    for (; j < n; ++j) {
        int s = ep[j];
        u16x8 v = *reinterpret_cast<const u16x8*>(V + (size_t)s * 80 + 40 + c * 8);
#pragma unroll
        for (int k = 0; k < 8; ++k) a0[k] += bf2f(v[k]);
    }
    float ci = 1.0f / fmaxf((float)dg, 1.0f);
    u16x8 sv = *reinterpret_cast<const u16x8*>(V + (size_t)i * 80 + c * 8);
    float o[8];
#pragma unroll
    for (int k = 0; k < 8; ++k)
        o[k] = bf2f(sv[k]) + (a0[k] + a1[k]) * ci + b2[c * 8 + k];
    float4* dst4 = reinterpret_cast<float4*>(logits + (size_t)i * 40 + c * 8);
    dst4[0] = make_float4(o[0], o[1], o[2], o[3]);
    dst4[1] = make_float4(o[4], o[5], o[6], o[7]);
}

extern "C" void kernel_launch(void* const* d_in, const int* in_sizes, int n_in,
                              void* d_out, int out_size, void* d_ws, size_t ws_size,
                              hipStream_t stream) {
    const float* x   = (const float*)d_in[0];
    const int*   ei  = (const int*)d_in[1];
    const float* Wl1 = (const float*)d_in[2];
    const float* Wr1 = (const float*)d_in[3];
    const float* b1  = (const float*)d_in[4];
    const float* Wl2 = (const float*)d_in[5];
    const float* Wr2 = (const float*)d_in[6];
    const float* b2  = (const float*)d_in[7];
    const int* src = ei;              // edge_index[0]
    const int* dst = ei + EDGES;      // edge_index[1]

    // Workspace (~40.3 MB):
    //   [0, 25.6M)       A1 [50000x256 bf16] = [xbf | mbf]
    //   [25.6M, 33.6M)   V  [50000x80 bf16]
    //   [33.6M, 40.0M)   esrc [50000*64 ushort]
    //   [40.0M, 40.2M)   deg [50000 int]
    //   [40.2M, ...)     w1p [32768 bf16 packed], w2p [10240 bf16 packed]
    char* ws = (char*)d_ws;
    ushort_t* A1   = (ushort_t*)ws;
    ushort_t* V    = (ushort_t*)(ws + 25600000);
    ushort_t* esrc = (ushort_t*)(ws + 33600000);
    int*      deg  = (int*)(ws + 40000000);
    ushort_t* w1p  = (ushort_t*)(ws + 40200000);
    ushort_t* w2p  = (ushort_t*)(ws + 40265536);

    float* logits_out = (float*)d_out;                   // 50000*40 f32
    float* emb_out    = logits_out + (size_t)NODES * 40; // 50000*128 f32

    zerok<<<98, 256, 0, stream>>>(deg);

    prep<<<9399, 256, 0, stream>>>(x, src, dst, Wr1, Wl1, Wr2, Wl2,
                                   deg, esrc, A1, w1p, w2p);

    aggx<<<3125, 256, 0, stream>>>(A1, esrc, deg);

    gemm12<<<(NODES + 63) / 64, 256, 0, stream>>>(A1, w1p, w2p, b1, emb_out, V, NODES);

    agg2<<<(NODES * 8 + 255) / 256, 256, 0, stream>>>(V, esrc, deg, b2, logits_out);
}